// Round 2
// baseline (650.072 us; speedup 1.0000x reference)
//
#include <hip/hip_runtime.h>

// Volume renderer (NeRF-style) — wave-per-ray.
// N_SAMPLES = 128, one 64-lane wave per ray, each lane owns samples (2i, 2i+1).
// transmittance via exp(-prefix_sum(sigma*delta)) instead of cumprod:
//   T_i = exp(-sum_{j<i} x_j),  w_i = T_i - T_{i+1}
// NUMERICS: lane 63's x1 contains the 1e10 sentinel delta. It must NOT enter
// the wave scan (inclusive-sum - s cancellation destroys the small prefix).
// It is only re-added when forming c1, whose sole use is exp(-c1) -> 0.
// All global reads are coalesced float2 (8 B/lane). Memory-bound: ~672 MB read.

#define FAR_DELTA 1e10f

__global__ __launch_bounds__(256) void volrender_kernel(
    const float* __restrict__ rgb,       // [N, 128, 3]
    const float* __restrict__ density,   // [N, 128, 1]
    const float* __restrict__ dist,      // [N, 128]
    float* __restrict__ out,             // [N, 3]
    int n_rays)
{
    const int lane = threadIdx.x & 63;
    const int ray  = (blockIdx.x * blockDim.x + threadIdx.x) >> 6;
    if (ray >= n_rays) return;

    const size_t base128 = (size_t)ray * 128;
    const float2* d2 = (const float2*)(dist    + base128);  // d[2i], d[2i+1]
    const float2* s2 = (const float2*)(density + base128);
    const float2* c2 = (const float2*)(rgb + (size_t)ray * 384 + 6 * lane);

    float2 dd = d2[lane];
    float2 ss = s2[lane];

    // delta for sample 2i  : d[2i+1] - d[2i]   (in-lane)
    // delta for sample 2i+1: d[2i+2] - d[2i+1] (neighbor lane's dd.x); lane 63 -> 1e10
    float dnext  = __shfl_down(dd.x, 1);
    float delta0 = dd.y - dd.x;
    float delta1 = (lane == 63) ? FAR_DELTA : (dnext - dd.y);

    float x0 = ss.x * delta0;
    float x1 = ss.y * delta1;

    // scan value: EXCLUDE the sentinel term on lane 63 (no higher lane needs
    // it, and including it destroys lane 63's own prefix via cancellation)
    float x1s = (lane == 63) ? 0.0f : x1;
    float s   = x0 + x1s;

    // inclusive wave scan of per-lane pair-sum
    float scan = s;
    #pragma unroll
    for (int off = 1; off < 64; off <<= 1) {
        float t = __shfl_up(scan, off);
        if (lane >= off) scan += t;
    }
    float cbase = scan - s;     // exclusive prefix: sum over samples < 2i
    float c0 = cbase + x0;      // inclusive through sample 2i
    float c1 = c0 + x1;         // inclusive through sample 2i+1 (real x1: huge on lane 63)

    float T0 = __expf(-cbase);  // transmittance entering sample 2i
    float T1 = __expf(-c0);     // entering sample 2i+1
    float T2 = __expf(-c1);     // leaving sample 2i+1 (lane 63: exp(-1e10*sigma) = 0)
    float w0 = T0 - T1;
    float w1 = T1 - T2;

    // rgb: 6 consecutive floats per lane, as 3 coalesced float2 loads
    float2 r0 = c2[0];          // rgb[2i].r,   rgb[2i].g
    float2 r1 = c2[1];          // rgb[2i].b,   rgb[2i+1].r
    float2 r2 = c2[2];          // rgb[2i+1].g, rgb[2i+1].b

    float accR = w0 * r0.x + w1 * r1.y;
    float accG = w0 * r0.y + w1 * r2.x;
    float accB = w0 * r1.x + w1 * r2.y;

    // wave-wide reduction to lane 0
    #pragma unroll
    for (int off = 32; off; off >>= 1) {
        accR += __shfl_down(accR, off);
        accG += __shfl_down(accG, off);
        accB += __shfl_down(accB, off);
    }

    if (lane == 0) {
        float* o = out + (size_t)ray * 3;
        o[0] = accR;
        o[1] = accG;
        o[2] = accB;
    }
}

extern "C" void kernel_launch(void* const* d_in, const int* in_sizes, int n_in,
                              void* d_out, int out_size, void* d_ws, size_t ws_size,
                              hipStream_t stream) {
    const float* rgb     = (const float*)d_in[0];
    const float* density = (const float*)d_in[1];
    const float* dist    = (const float*)d_in[2];
    float* out = (float*)d_out;

    const int n_rays = in_sizes[2] / 128;   // distances is [N, 128]

    // one wave (64 lanes) per ray; 4 rays per 256-thread block
    const int block = 256;
    const int rays_per_block = block / 64;
    const int grid = (n_rays + rays_per_block - 1) / rays_per_block;

    volrender_kernel<<<grid, block, 0, stream>>>(rgb, density, dist, out, n_rays);
}